// Round 1
// baseline (952.311 us; speedup 1.0000x reference)
//
#include <hip/hip_runtime.h>

#define DIM 4096

typedef __bf16 bf16x8 __attribute__((ext_vector_type(8)));
typedef float floatx4 __attribute__((ext_vector_type(4)));

// ---------------- W-build kernels (total ~0.27 GFLOP) ----------------
// core0 (4,1,8,4): [a][i][v] = a*32 + i*4 + v
// core1 (4,8,8,4): [b][i][j][w] = b*256 + i*32 + j*4 + w
// core2 (8,8,8,8): [c][j][k][x] = c*512 + j*64 + k*8 + x
// core3 (8,8,8,8): [d][k][l][y] = d*512 + k*64 + l*8 + y
// core4 (4,8,1,4): [e][l][z] = e*32 + l*4 + z

// K01[ab=16][j=8][vw=16], K34[de=32][k=8][yz=32]
__global__ void build_small(const float* __restrict__ c0, const float* __restrict__ c1,
                            const float* __restrict__ c3, const float* __restrict__ c4,
                            float* __restrict__ K01, float* __restrict__ K34) {
  int t = blockIdx.x * 256 + threadIdx.x;
  if (t < 2048) {
    int vw = t & 15, j = (t >> 4) & 7, ab = t >> 7;
    int a = ab >> 2, b = ab & 3, v = vw >> 2, w = vw & 3;
    float s = 0.f;
#pragma unroll
    for (int i = 0; i < 8; ++i)
      s += c0[a * 32 + i * 4 + v] * c1[b * 256 + i * 32 + j * 4 + w];
    K01[t] = s;
  } else if (t < 2048 + 8192) {
    int u = t - 2048;
    int yz = u & 31, k = (u >> 5) & 7, de = u >> 8;
    int d = de >> 2, e = de & 3, y = yz >> 2, z = yz & 3;
    float s = 0.f;
#pragma unroll
    for (int l = 0; l < 8; ++l)
      s += c3[d * 512 + k * 64 + l * 8 + y] * c4[e * 32 + l * 4 + z];
    K34[u] = s;
  }
}

// K012[abc=128][k=8][vwx=128]
__global__ void build_k012(const float* __restrict__ K01, const float* __restrict__ c2,
                           float* __restrict__ K012) {
  int t = blockIdx.x * 256 + threadIdx.x;  // 131072 threads
  int vwx = t & 127, k = (t >> 7) & 7, abc = t >> 10;
  int ab = abc >> 3, c = abc & 7, vw = vwx >> 3, x = vwx & 7;
  float s = 0.f;
#pragma unroll
  for (int j = 0; j < 8; ++j)
    s += K01[ab * 128 + j * 16 + vw] * c2[c * 512 + j * 64 + k * 8 + x];
  K012[t] = s;
}

// WT[o=4096][in=4096] bf16; o = vwx*32+yz, in = abc*32+de
__global__ void build_wt(const float* __restrict__ K012, const float* __restrict__ K34,
                         __bf16* __restrict__ WT) {
  int t = blockIdx.x * 256 + threadIdx.x;  // 16777216 threads
  int in = t & 4095, o = t >> 12;
  int de = in & 31, abc = in >> 5;
  int yz = o & 31, vwx = o >> 5;
  float s = 0.f;
#pragma unroll
  for (int k = 0; k < 8; ++k)
    s += K012[abc * 1024 + k * 128 + vwx] * K34[de * 256 + k * 32 + yz];
  WT[t] = (__bf16)s;
}

// ---------------- GEMM: C[8192][4096] = X(fp32->bf16) * WT^T + bias ----------------
__device__ __forceinline__ void async_ld16(void* lds, const void* g) {
  __builtin_amdgcn_global_load_lds(
      (const __attribute__((address_space(1))) unsigned int*)g,
      (__attribute__((address_space(3))) unsigned int*)lds, 16, 0, 0);
}

__global__ __launch_bounds__(256) void gemm_xw(const float* __restrict__ X,
                                               const __bf16* __restrict__ WT,
                                               const float* __restrict__ bias,
                                               float* __restrict__ C) {
  // A tile padded to 40 elems/row (80B stride = 20 dwords -> conflict-free b128)
  __shared__ __bf16 As[128 * 40];
  __shared__ __bf16 Bs[128 * 32];

  const int tid = threadIdx.x;
  const int n0 = (blockIdx.x & 31) * 128;
  const int m0 = (blockIdx.x >> 5) * 128;

  const int wave = tid >> 6, lane = tid & 63;
  const int wm = (wave >> 1) * 64, wn = (wave & 1) * 64;
  const int lm = lane & 15, kq = lane >> 4;

  floatx4 acc[4][4] = {};

  // A staging: thread t -> row t/2, 16-float chunk (t&1)
  const int ar = tid >> 1;
  const int ac = (tid & 1) * 16;
  const float* xp = X + (long)(m0 + ar) * DIM + ac;
  __bf16* as_dst = &As[ar * 40 + ac];

  // B staging: lane-linear LDS dest (global_load_lds requirement);
  // XOR-swizzle which global 16B chunk each lane fetches to spread LDS read banks.
  const int u0 = tid, u1 = 256 + tid;
  const int r0 = u0 >> 2, r1 = u1 >> 2;
  const int ch0 = (u0 & 3) ^ (r0 & 3), ch1 = (u1 & 3) ^ (r1 & 3);
  const __bf16* wp0 = WT + (long)(n0 + r0) * DIM + ch0 * 8;
  const __bf16* wp1 = WT + (long)(n0 + r1) * DIM + ch1 * 8;

  // prologue: prefetch first A chunk into regs
  float4 a0 = *(const float4*)(xp);
  float4 a1 = *(const float4*)(xp + 4);
  float4 a2 = *(const float4*)(xp + 8);
  float4 a3 = *(const float4*)(xp + 12);

#pragma unroll 1
  for (int k0 = 0; k0 < DIM; k0 += 32) {
    // async B -> LDS
    async_ld16(&Bs[u0 * 8], wp0 + k0);
    async_ld16(&Bs[u1 * 8], wp1 + k0);

    // convert A regs -> bf16 -> LDS (two b128 writes)
    bf16x8 w0, w1;
    w0[0] = (__bf16)a0.x; w0[1] = (__bf16)a0.y; w0[2] = (__bf16)a0.z; w0[3] = (__bf16)a0.w;
    w0[4] = (__bf16)a1.x; w0[5] = (__bf16)a1.y; w0[6] = (__bf16)a1.z; w0[7] = (__bf16)a1.w;
    w1[0] = (__bf16)a2.x; w1[1] = (__bf16)a2.y; w1[2] = (__bf16)a2.z; w1[3] = (__bf16)a2.w;
    w1[4] = (__bf16)a3.x; w1[5] = (__bf16)a3.y; w1[6] = (__bf16)a3.z; w1[7] = (__bf16)a3.w;
    *(bf16x8*)(as_dst) = w0;
    *(bf16x8*)(as_dst + 8) = w1;

    // prefetch next A chunk (global->reg, overlaps compute)
    if (k0 + 32 < DIM) {
      a0 = *(const float4*)(xp + k0 + 32);
      a1 = *(const float4*)(xp + k0 + 36);
      a2 = *(const float4*)(xp + k0 + 40);
      a3 = *(const float4*)(xp + k0 + 44);
    }
    __syncthreads();

    bf16x8 af[4], bfr[4];
#pragma unroll
    for (int mi = 0; mi < 4; ++mi)
      af[mi] = *(const bf16x8*)&As[(wm + mi * 16 + lm) * 40 + kq * 8];
#pragma unroll
    for (int ni = 0; ni < 4; ++ni) {
      int rr = wn + ni * 16 + lm;
      bfr[ni] = *(const bf16x8*)&Bs[rr * 32 + ((kq ^ (rr & 3)) * 8)];
    }
#pragma unroll
    for (int mi = 0; mi < 4; ++mi)
#pragma unroll
      for (int ni = 0; ni < 4; ++ni)
        acc[mi][ni] = __builtin_amdgcn_mfma_f32_16x16x32_bf16(af[mi], bfr[ni], acc[mi][ni], 0, 0, 0);
    __syncthreads();
  }

  // epilogue: C/D layout col=lane&15, row=(lane>>4)*4+reg
  float bv[4];
#pragma unroll
  for (int ni = 0; ni < 4; ++ni) bv[ni] = bias[n0 + wn + ni * 16 + lm];
#pragma unroll
  for (int mi = 0; mi < 4; ++mi) {
    long mr = m0 + wm + mi * 16 + kq * 4;
#pragma unroll
    for (int ni = 0; ni < 4; ++ni) {
      float* cp = C + mr * DIM + (n0 + wn + ni * 16 + lm);
      cp[0]       = acc[mi][ni][0] + bv[ni];
      cp[DIM]     = acc[mi][ni][1] + bv[ni];
      cp[2 * DIM] = acc[mi][ni][2] + bv[ni];
      cp[3 * DIM] = acc[mi][ni][3] + bv[ni];
    }
  }
}

extern "C" void kernel_launch(void* const* d_in, const int* in_sizes, int n_in,
                              void* d_out, int out_size, void* d_ws, size_t ws_size,
                              hipStream_t stream) {
  const float* x    = (const float*)d_in[0];
  const float* c0   = (const float*)d_in[1];
  const float* c1   = (const float*)d_in[2];
  const float* c2   = (const float*)d_in[3];
  const float* c3   = (const float*)d_in[4];
  const float* c4   = (const float*)d_in[5];
  const float* bias = (const float*)d_in[6];
  float* out = (float*)d_out;

  // ws layout: WT bf16 (33,554,432 B) | K012 fp32 (524,288 B) | K01 (8,192 B) | K34 (32,768 B)
  char* ws = (char*)d_ws;
  __bf16* WT  = (__bf16*)ws;
  float* K012 = (float*)(ws + 33554432);
  float* K01  = (float*)(ws + 33554432 + 524288);
  float* K34  = (float*)(ws + 33554432 + 524288 + 8192);

  build_small<<<40, 256, 0, stream>>>(c0, c1, c3, c4, K01, K34);
  build_k012<<<512, 256, 0, stream>>>(K01, c2, K012);
  build_wt<<<65536, 256, 0, stream>>>(K012, K34, WT);
  gemm_xw<<<2048, 256, 0, stream>>>(x, WT, bias, out);
}

// Round 2
// 548.131 us; speedup vs baseline: 1.7374x; 1.7374x over previous
//
#include <hip/hip_runtime.h>

#define DIM 4096

typedef __bf16 bf16x8 __attribute__((ext_vector_type(8)));
typedef float floatx4 __attribute__((ext_vector_type(4)));

// ---------------- W-build kernels (total ~0.27 GFLOP) ----------------
// core0 (4,1,8,4): [a][i][v] = a*32 + i*4 + v
// core1 (4,8,8,4): [b][i][j][w] = b*256 + i*32 + j*4 + w
// core2 (8,8,8,8): [c][j][k][x] = c*512 + j*64 + k*8 + x
// core3 (8,8,8,8): [d][k][l][y] = d*512 + k*64 + l*8 + y
// core4 (4,8,1,4): [e][l][z] = e*32 + l*4 + z

// K01[ab=16][j=8][vw=16]; K34T[k=8][yz=32][de=32]  (transposed so de is contiguous)
__global__ void build_small(const float* __restrict__ c0, const float* __restrict__ c1,
                            const float* __restrict__ c3, const float* __restrict__ c4,
                            float* __restrict__ K01, float* __restrict__ K34T) {
  int t = blockIdx.x * 256 + threadIdx.x;
  if (t < 2048) {
    int vw = t & 15, j = (t >> 4) & 7, ab = t >> 7;
    int a = ab >> 2, b = ab & 3, v = vw >> 2, w = vw & 3;
    float s = 0.f;
#pragma unroll
    for (int i = 0; i < 8; ++i)
      s += c0[a * 32 + i * 4 + v] * c1[b * 256 + i * 32 + j * 4 + w];
    K01[t] = s;
  } else if (t < 2048 + 8192) {
    int u = t - 2048;
    int yz = u & 31, k = (u >> 5) & 7, de = u >> 8;
    int d = de >> 2, e = de & 3, y = yz >> 2, z = yz & 3;
    float s = 0.f;
#pragma unroll
    for (int l = 0; l < 8; ++l)
      s += c3[d * 512 + k * 64 + l * 8 + y] * c4[e * 32 + l * 4 + z];
    K34T[k * 1024 + yz * 32 + de] = s;
  }
}

// K012[abc=128][k=8][vwx=128]
__global__ void build_k012(const float* __restrict__ K01, const float* __restrict__ c2,
                           float* __restrict__ K012) {
  int t = blockIdx.x * 256 + threadIdx.x;  // 131072 threads
  int vwx = t & 127, k = (t >> 7) & 7, abc = t >> 10;
  int ab = abc >> 3, c = abc & 7, vw = vwx >> 3, x = vwx & 7;
  float s = 0.f;
#pragma unroll
  for (int j = 0; j < 8; ++j)
    s += K01[ab * 128 + j * 16 + vw] * c2[c * 512 + j * 64 + k * 8 + x];
  K012[t] = s;
}

// WT[o=4096][in=4096] bf16; o = vwx*32+yz, in = abc*32+de
// lane-fast index is `in` -> de contiguous via K34T, abc gives wave-broadcast K012 reads
__global__ void build_wt(const float* __restrict__ K012, const float* __restrict__ K34T,
                         __bf16* __restrict__ WT) {
  int t = blockIdx.x * 256 + threadIdx.x;  // 16777216 threads
  int in = t & 4095, o = t >> 12;
  int de = in & 31, abc = in >> 5;
  int yz = o & 31, vwx = o >> 5;
  float s = 0.f;
#pragma unroll
  for (int k = 0; k < 8; ++k)
    s += K012[abc * 1024 + k * 128 + vwx] * K34T[k * 1024 + yz * 32 + de];
  WT[t] = (__bf16)s;
}

// X fp32 -> bf16, 8 elems/thread
__global__ void x_to_bf16(const float* __restrict__ X, __bf16* __restrict__ Xb) {
  long t = (long)blockIdx.x * 256 + threadIdx.x;  // 4,194,304 threads
  float4 a = ((const float4*)X)[t * 2];
  float4 b = ((const float4*)X)[t * 2 + 1];
  bf16x8 w;
  w[0] = (__bf16)a.x; w[1] = (__bf16)a.y; w[2] = (__bf16)a.z; w[3] = (__bf16)a.w;
  w[4] = (__bf16)b.x; w[5] = (__bf16)b.y; w[6] = (__bf16)b.z; w[7] = (__bf16)b.w;
  ((bf16x8*)Xb)[t] = w;
}

__device__ __forceinline__ void async_ld16(void* lds, const void* g) {
  __builtin_amdgcn_global_load_lds(
      (const __attribute__((address_space(1))) unsigned int*)g,
      (__attribute__((address_space(3))) unsigned int*)lds, 16, 0, 0);
}

// ---------------- GEMM (bf16 A): C[8192][4096] = Xb * WT^T + bias ----------------
// m97 structure: 128x128 tile, BK=64, both tiles via global_load_lds(16B),
// XOR chunk swizzle pc = c ^ (row&7) -> conflict-free b128 frag reads.
__global__ __launch_bounds__(256) void gemm_bf(const __bf16* __restrict__ A,
                                               const __bf16* __restrict__ WT,
                                               const float* __restrict__ bias,
                                               float* __restrict__ C) {
  __shared__ __bf16 As[128 * 64];
  __shared__ __bf16 Bs[128 * 64];

  const int tid = threadIdx.x;
  const int n0 = (blockIdx.x & 31) * 128;
  const int m0 = (blockIdx.x >> 5) * 128;

  const int wave = tid >> 6, lane = tid & 63;
  const int wm = (wave >> 1) * 64, wn = (wave & 1) * 64;
  const int lm = lane & 15, kq = lane >> 4;

  floatx4 acc[4][4] = {};

  // staging: 4 16B-chunks each of A and B per thread; chunk q = tid + j*256,
  // row r = q>>3, physical chunk pc = q&7 holds global chunk c = pc ^ (r&7)
  const __bf16* agp[4];
  const __bf16* bgp[4];
  int ldsoff[4];
#pragma unroll
  for (int j = 0; j < 4; ++j) {
    int q = tid + j * 256;
    int r = q >> 3, pc = q & 7;
    int c = pc ^ (r & 7);
    ldsoff[j] = q * 8;  // elements (16B chunks)
    agp[j] = A + (long)(m0 + r) * DIM + c * 8;
    bgp[j] = WT + (long)(n0 + r) * DIM + c * 8;
  }

#pragma unroll 1
  for (int k0 = 0; k0 < DIM; k0 += 64) {
#pragma unroll
    for (int j = 0; j < 4; ++j) async_ld16(&As[ldsoff[j]], agp[j] + k0);
#pragma unroll
    for (int j = 0; j < 4; ++j) async_ld16(&Bs[ldsoff[j]], bgp[j] + k0);
    __syncthreads();

#pragma unroll
    for (int kh = 0; kh < 2; ++kh) {
      bf16x8 af[4], bfr[4];
#pragma unroll
      for (int mi = 0; mi < 4; ++mi) {
        int r = wm + mi * 16 + lm;
        int pc = (kh * 4 + kq) ^ (r & 7);
        af[mi] = *(const bf16x8*)&As[r * 64 + pc * 8];
      }
#pragma unroll
      for (int ni = 0; ni < 4; ++ni) {
        int r = wn + ni * 16 + lm;
        int pc = (kh * 4 + kq) ^ (r & 7);
        bfr[ni] = *(const bf16x8*)&Bs[r * 64 + pc * 8];
      }
#pragma unroll
      for (int mi = 0; mi < 4; ++mi)
#pragma unroll
        for (int ni = 0; ni < 4; ++ni)
          acc[mi][ni] = __builtin_amdgcn_mfma_f32_16x16x32_bf16(af[mi], bfr[ni], acc[mi][ni], 0, 0, 0);
    }
    __syncthreads();
  }

  // epilogue: C/D layout col=lane&15, row=(lane>>4)*4+reg
  float bv[4];
#pragma unroll
  for (int ni = 0; ni < 4; ++ni) bv[ni] = bias[n0 + wn + ni * 16 + lm];
#pragma unroll
  for (int mi = 0; mi < 4; ++mi) {
    long mr = m0 + wm + mi * 16 + kq * 4;
#pragma unroll
    for (int ni = 0; ni < 4; ++ni) {
      float* cp = C + mr * DIM + (n0 + wn + ni * 16 + lm);
      cp[0]       = acc[mi][ni][0] + bv[ni];
      cp[DIM]     = acc[mi][ni][1] + bv[ni];
      cp[2 * DIM] = acc[mi][ni][2] + bv[ni];
      cp[3 * DIM] = acc[mi][ni][3] + bv[ni];
    }
  }
}

// ---------------- Fallback GEMM (fp32 A fused conversion, round-1) ----------------
__global__ __launch_bounds__(256) void gemm_xw(const float* __restrict__ X,
                                               const __bf16* __restrict__ WT,
                                               const float* __restrict__ bias,
                                               float* __restrict__ C) {
  __shared__ __bf16 As[128 * 40];
  __shared__ __bf16 Bs[128 * 32];

  const int tid = threadIdx.x;
  const int n0 = (blockIdx.x & 31) * 128;
  const int m0 = (blockIdx.x >> 5) * 128;

  const int wave = tid >> 6, lane = tid & 63;
  const int wm = (wave >> 1) * 64, wn = (wave & 1) * 64;
  const int lm = lane & 15, kq = lane >> 4;

  floatx4 acc[4][4] = {};

  const int ar = tid >> 1;
  const int ac = (tid & 1) * 16;
  const float* xp = X + (long)(m0 + ar) * DIM + ac;
  __bf16* as_dst = &As[ar * 40 + ac];

  const int u0 = tid, u1 = 256 + tid;
  const int r0 = u0 >> 2, r1 = u1 >> 2;
  const int ch0 = (u0 & 3) ^ (r0 & 3), ch1 = (u1 & 3) ^ (r1 & 3);
  const __bf16* wp0 = WT + (long)(n0 + r0) * DIM + ch0 * 8;
  const __bf16* wp1 = WT + (long)(n0 + r1) * DIM + ch1 * 8;

  float4 a0 = *(const float4*)(xp);
  float4 a1 = *(const float4*)(xp + 4);
  float4 a2 = *(const float4*)(xp + 8);
  float4 a3 = *(const float4*)(xp + 12);

#pragma unroll 1
  for (int k0 = 0; k0 < DIM; k0 += 32) {
    async_ld16(&Bs[u0 * 8], wp0 + k0);
    async_ld16(&Bs[u1 * 8], wp1 + k0);

    bf16x8 w0, w1;
    w0[0] = (__bf16)a0.x; w0[1] = (__bf16)a0.y; w0[2] = (__bf16)a0.z; w0[3] = (__bf16)a0.w;
    w0[4] = (__bf16)a1.x; w0[5] = (__bf16)a1.y; w0[6] = (__bf16)a1.z; w0[7] = (__bf16)a1.w;
    w1[0] = (__bf16)a2.x; w1[1] = (__bf16)a2.y; w1[2] = (__bf16)a2.z; w1[3] = (__bf16)a2.w;
    w1[4] = (__bf16)a3.x; w1[5] = (__bf16)a3.y; w1[6] = (__bf16)a3.z; w1[7] = (__bf16)a3.w;
    *(bf16x8*)(as_dst) = w0;
    *(bf16x8*)(as_dst + 8) = w1;

    if (k0 + 32 < DIM) {
      a0 = *(const float4*)(xp + k0 + 32);
      a1 = *(const float4*)(xp + k0 + 36);
      a2 = *(const float4*)(xp + k0 + 40);
      a3 = *(const float4*)(xp + k0 + 44);
    }
    __syncthreads();

    bf16x8 af[4], bfr[4];
#pragma unroll
    for (int mi = 0; mi < 4; ++mi)
      af[mi] = *(const bf16x8*)&As[(wm + mi * 16 + lm) * 40 + kq * 8];
#pragma unroll
    for (int ni = 0; ni < 4; ++ni) {
      int rr = wn + ni * 16 + lm;
      bfr[ni] = *(const bf16x8*)&Bs[rr * 32 + ((kq ^ (rr & 3)) * 8)];
    }
#pragma unroll
    for (int mi = 0; mi < 4; ++mi)
#pragma unroll
      for (int ni = 0; ni < 4; ++ni)
        acc[mi][ni] = __builtin_amdgcn_mfma_f32_16x16x32_bf16(af[mi], bfr[ni], acc[mi][ni], 0, 0, 0);
    __syncthreads();
  }

  float bv[4];
#pragma unroll
  for (int ni = 0; ni < 4; ++ni) bv[ni] = bias[n0 + wn + ni * 16 + lm];
#pragma unroll
  for (int mi = 0; mi < 4; ++mi) {
    long mr = m0 + wm + mi * 16 + kq * 4;
#pragma unroll
    for (int ni = 0; ni < 4; ++ni) {
      float* cp = C + mr * DIM + (n0 + wn + ni * 16 + lm);
      cp[0]       = acc[mi][ni][0] + bv[ni];
      cp[DIM]     = acc[mi][ni][1] + bv[ni];
      cp[2 * DIM] = acc[mi][ni][2] + bv[ni];
      cp[3 * DIM] = acc[mi][ni][3] + bv[ni];
    }
  }
}

extern "C" void kernel_launch(void* const* d_in, const int* in_sizes, int n_in,
                              void* d_out, int out_size, void* d_ws, size_t ws_size,
                              hipStream_t stream) {
  const float* x    = (const float*)d_in[0];
  const float* c0   = (const float*)d_in[1];
  const float* c1   = (const float*)d_in[2];
  const float* c2   = (const float*)d_in[3];
  const float* c3   = (const float*)d_in[4];
  const float* c4   = (const float*)d_in[5];
  const float* bias = (const float*)d_in[6];
  float* out = (float*)d_out;

  const size_t XB_SZ = 67108864;    // 8192*4096 bf16
  const size_t WT_SZ = 33554432;    // 4096*4096 bf16
  const size_t K012_SZ = 524288;    // 128*8*128 fp32
  const size_t K01_SZ = 8192;
  const size_t K34_SZ = 32768;
  char* ws = (char*)d_ws;

  if (ws_size >= XB_SZ + WT_SZ + K012_SZ + K01_SZ + K34_SZ) {
    __bf16* Xb  = (__bf16*)ws;
    __bf16* WT  = (__bf16*)(ws + XB_SZ);
    float* K012 = (float*)(ws + XB_SZ + WT_SZ);
    float* K01  = (float*)(ws + XB_SZ + WT_SZ + K012_SZ);
    float* K34T = (float*)(ws + XB_SZ + WT_SZ + K012_SZ + K01_SZ);

    build_small<<<40, 256, 0, stream>>>(c0, c1, c3, c4, K01, K34T);
    x_to_bf16<<<16384, 256, 0, stream>>>(x, Xb);
    build_k012<<<512, 256, 0, stream>>>(K01, c2, K012);
    build_wt<<<65536, 256, 0, stream>>>(K012, K34T, WT);
    gemm_bf<<<2048, 256, 0, stream>>>(Xb, WT, bias, out);
  } else {
    __bf16* WT  = (__bf16*)ws;
    float* K012 = (float*)(ws + WT_SZ);
    float* K01  = (float*)(ws + WT_SZ + K012_SZ);
    float* K34T = (float*)(ws + WT_SZ + K012_SZ + K01_SZ);

    build_small<<<40, 256, 0, stream>>>(c0, c1, c3, c4, K01, K34T);
    build_k012<<<512, 256, 0, stream>>>(K01, c2, K012);
    build_wt<<<65536, 256, 0, stream>>>(K012, K34T, WT);
    gemm_xw<<<2048, 256, 0, stream>>>(x, WT, bias, out);
  }
}